// Round 11
// baseline (876.400 us; speedup 1.0000x reference)
//
#include <hip/hip_runtime.h>

typedef short bf16x8 __attribute__((ext_vector_type(8)));
typedef float f32x4 __attribute__((ext_vector_type(4)));

#define LN10000_32 0.2878231406211853f  // ln(10000)/32

__device__ __forceinline__ unsigned short f2bf(float f) {
  union { float f; unsigned int u; } v; v.f = f;
  unsigned int r = v.u + 0x7fffu + ((v.u >> 16) & 1u);
  return (unsigned short)(r >> 16);
}
__device__ __forceinline__ float bf2f(unsigned short h) {
  union { unsigned int u; float f; } v; v.u = ((unsigned int)h) << 16;
  return v.f;
}

__device__ __forceinline__ void stage16(const unsigned short* g, unsigned short* lds_base, int lane) {
#if __has_builtin(__builtin_amdgcn_global_load_lds)
  (void)lane;
  __builtin_amdgcn_global_load_lds((const __attribute__((address_space(1))) void*)g,
                                   (__attribute__((address_space(3))) void*)lds_base,
                                   16, 0, 0);
#else
  *(bf16x8*)((char*)lds_base + lane * 16) = *(const bf16x8*)g;
#endif
}

// ---------------- min/max of the two x_ref_attn_map rows ---------------------
__global__ void minmax_kernel(const float* __restrict__ xmap, float* __restrict__ mm) {
  __shared__ float red[4][256];
  int t = threadIdx.x;
  float mn0 = 3.4e38f, mx0 = -3.4e38f, mn1 = 3.4e38f, mx1 = -3.4e38f;
  for (int i = t; i < 32760; i += 256) {
    float a = xmap[i];          mn0 = fminf(mn0, a); mx0 = fmaxf(mx0, a);
    float b = xmap[32760 + i];  mn1 = fminf(mn1, b); mx1 = fmaxf(mx1, b);
  }
  red[0][t] = mn0; red[1][t] = mx0; red[2][t] = mn1; red[3][t] = mx1;
  __syncthreads();
  for (int s = 128; s > 0; s >>= 1) {
    if (t < s) {
      red[0][t] = fminf(red[0][t], red[0][t + s]);
      red[1][t] = fmaxf(red[1][t], red[1][t + s]);
      red[2][t] = fminf(red[2][t], red[2][t + s]);
      red[3][t] = fmaxf(red[3][t], red[3][t + s]);
    }
    __syncthreads();
  }
  if (t == 0) { mm[0] = red[0][0]; mm[1] = red[1][0]; mm[2] = red[2][0]; mm[3] = red[3][0]; }
}

// ---------------- normalized position -> cos/sin table (32760 x 32) ----------
__global__ void pos_table_kernel(const float* __restrict__ xmap, const float* __restrict__ mm,
                                 float2* __restrict__ tab) {
  int n = blockIdx.x * 256 + threadIdx.x;
  if (n >= 32760) return;
  float m0 = xmap[n], m1 = xmap[32760 + n];
  float pos;
  if (m1 > m0) pos = (m1 - mm[2]) / (mm[3] - mm[2] + 1e-8f) * 4.0f + 20.0f;
  else         pos = (m0 - mm[0]) / (mm[1] - mm[0] + 1e-8f) * 4.0f;
  #pragma unroll
  for (int j = 0; j < 32; j++) {
    float invf = __expf(-(float)j * LN10000_32);
    float f = pos * invf;
    float s, c;
    sincosf(f, &s, &c);
    tab[(long)n * 32 + j] = make_float2(c, s);
  }
}

// ---------------- casts -------------------------------------------------------
// x: 32768 rows x 2048 cols (rows >= 32760 zero-padded), grid-stride.
__global__ void cast_x_kernel(const float* __restrict__ src, unsigned short* __restrict__ dst) {
  const long total8 = (long)32768 * 256;
  for (long g = (long)blockIdx.x * 256 + threadIdx.x; g < total8; g += (long)gridDim.x * 256) {
    long r = g >> 8;
    int c = (int)(g & 255) * 8;
    bf16x8 o;
    if (r < 32760) {
      const float4* s = (const float4*)(src + r * 2048 + c);
      float4 a = s[0], b = s[1];
      o[0] = (short)f2bf(a.x); o[1] = (short)f2bf(a.y); o[2] = (short)f2bf(a.z); o[3] = (short)f2bf(a.w);
      o[4] = (short)f2bf(b.x); o[5] = (short)f2bf(b.y); o[6] = (short)f2bf(b.z); o[7] = (short)f2bf(b.w);
    } else {
      #pragma unroll
      for (int t = 0; t < 8; t++) o[t] = 0;
    }
    *(bf16x8*)(dst + r * 2048 + c) = o;
  }
}

// all three weight matrices in one launch: [0,n0) -> q_w, [n0,n1) -> kv_w, rest -> proj_w
__global__ void cast_weights_kernel(const float* __restrict__ qw, const float* __restrict__ kvw,
                                    const float* __restrict__ pw,
                                    unsigned short* __restrict__ qwb, unsigned short* __restrict__ kvwb,
                                    unsigned short* __restrict__ pwb) {
  const long n0 = 524288, n1 = 917504, n2 = 1441792;  // groups of 8
  long i = (long)blockIdx.x * 256 + threadIdx.x;
  if (i >= n2) return;
  const float* src; unsigned short* dst; long j;
  if (i < n0)      { src = qw;  dst = qwb;  j = i; }
  else if (i < n1) { src = kvw; dst = kvwb; j = i - n0; }
  else             { src = pw;  dst = pwb;  j = i - n1; }
  const float4* s = (const float4*)(src + j * 8);
  float4 a = s[0], b = s[1];
  bf16x8 o;
  o[0] = (short)f2bf(a.x); o[1] = (short)f2bf(a.y); o[2] = (short)f2bf(a.z); o[3] = (short)f2bf(a.w);
  o[4] = (short)f2bf(b.x); o[5] = (short)f2bf(b.y); o[6] = (short)f2bf(b.z); o[7] = (short)f2bf(b.w);
  *(bf16x8*)(dst + j * 8) = o;
}

__global__ void cast_ehs_kernel(const float* __restrict__ src, unsigned short* __restrict__ dst) {
  int idx = blockIdx.x * 256 + threadIdx.x;
  int r = idx / 96, c = (idx % 96) * 8;
  bf16x8 o;
  if (r < 672) {
    const float4* s = (const float4*)(src + (long)r * 768 + c);
    float4 a = s[0], b = s[1];
    o[0] = (short)f2bf(a.x); o[1] = (short)f2bf(a.y); o[2] = (short)f2bf(a.z); o[3] = (short)f2bf(a.w);
    o[4] = (short)f2bf(b.x); o[5] = (short)f2bf(b.y); o[6] = (short)f2bf(b.z); o[7] = (short)f2bf(b.w);
  } else {
    #pragma unroll
    for (int t = 0; t < 8; t++) o[t] = 0;
  }
  *(bf16x8*)(dst + (long)r * 768 + c) = o;
}

// ---------------- small GEMM (128x128 m97-style) for KV projection -----------
template <int OUTF>
__global__ __launch_bounds__(256, 2)
void gemm_bt(const unsigned short* __restrict__ A, const unsigned short* __restrict__ B,
             const float* __restrict__ bias, void* __restrict__ C,
             int M, int N, int K, int M_valid) {
  __shared__ unsigned short As[128 * 32];
  __shared__ unsigned short Bs[128 * 32];
  int mt = blockIdx.x, nt = blockIdx.y;
  const int m0 = mt * 128;
  const int n0 = nt * 128;
  const int tid = threadIdx.x;
  const int wave = tid >> 6;
  const int lane = tid & 63;
  const int wr = wave >> 1, wc = wave & 1;
  const int lrow = lane >> 2, lcol = lane & 3;

  f32x4 acc[4][4];
  #pragma unroll
  for (int i = 0; i < 4; i++)
    #pragma unroll
    for (int j = 0; j < 4; j++) acc[i][j] = (f32x4){0.f, 0.f, 0.f, 0.f};

  const unsigned short* gA = A + (long)(m0 + wave * 32 + lrow) * K + lcol * 8;
  const unsigned short* gB = B + (long)(n0 + wave * 32 + lrow) * K + lcol * 8;
  unsigned short* lA0 = &As[wave * 1024];
  unsigned short* lA1 = &As[wave * 1024 + 512];
  unsigned short* lB0 = &Bs[wave * 1024];
  unsigned short* lB1 = &Bs[wave * 1024 + 512];

  for (int k0 = 0; k0 < K; k0 += 32) {
    stage16(gA + k0, lA0, lane);
    stage16(gA + k0 + 16 * K, lA1, lane);
    stage16(gB + k0, lB0, lane);
    stage16(gB + k0 + 16 * K, lB1, lane);
    __syncthreads();
    bf16x8 af[4], bfr[4];
    const int kq = (lane >> 4) * 8;
    const int rr = lane & 15;
    #pragma unroll
    for (int mi = 0; mi < 4; mi++) af[mi] = *(const bf16x8*)&As[(wr * 64 + mi * 16 + rr) * 32 + kq];
    #pragma unroll
    for (int ni = 0; ni < 4; ni++) bfr[ni] = *(const bf16x8*)&Bs[(wc * 64 + ni * 16 + rr) * 32 + kq];
    #pragma unroll
    for (int mi = 0; mi < 4; mi++)
      #pragma unroll
      for (int ni = 0; ni < 4; ni++)
        acc[mi][ni] = __builtin_amdgcn_mfma_f32_16x16x32_bf16(af[mi], bfr[ni], acc[mi][ni], 0, 0, 0);
    __syncthreads();
  }

  const int colL = lane & 15, rq = (lane >> 4) * 4;
  #pragma unroll
  for (int mi = 0; mi < 4; mi++) {
    #pragma unroll
    for (int ni = 0; ni < 4; ni++) {
      int col = n0 + wc * 64 + ni * 16 + colL;
      float bv = bias[col];
      #pragma unroll
      for (int r = 0; r < 4; r++) {
        int row = m0 + wr * 64 + mi * 16 + rq + r;
        if (row < M_valid) {
          float v = acc[mi][ni][r] + bv;
          if (OUTF) ((float*)C)[(long)row * N + col] = v;
          else      ((unsigned short*)C)[(long)row * N + col] = f2bf(v);
        }
      }
    }
  }
}

// ---------------- big GEMM: 256x256, BK=64, dbuf, 8-phase counted-vmcnt ------
// Round-3 version, frozen (measured best: pass, ~330 us, 36% MfmaUtil).
template <int OUTF>
__global__ __launch_bounds__(512, 2)
void gemm256(const unsigned short* __restrict__ A, const unsigned short* __restrict__ B,
             const float* __restrict__ bias, void* __restrict__ C,
             int K, int N, int M_valid) {
  extern __shared__ __align__(16) unsigned short lds[];  // 65536 ushorts
  const int NT = K >> 6;
  const int NI = NT >> 1;
  const int orig = blockIdx.x;
  const int cpx = (int)gridDim.x >> 3;
  const int wgid = (orig & 7) * cpx + (orig >> 3);
  const int nt = wgid & 7;
  const int mt = wgid >> 3;
  const int m0 = mt << 8, n0 = nt << 8;
  const int tid = threadIdx.x;
  const int w = tid >> 6, l = tid & 63;
  const int wr = w >> 2, wc = w & 3;
  const int i = l & 15, kq = l >> 4;

  const int swz0 = ((kq) ^ (i & 7)) * 8;
  const int swz1 = ((4 + kq) ^ (i & 7)) * 8;
  const int aoff = wr * 8192 + i * 64;
  const int boff = 16384 + (wc >> 1) * 8192 + (wc & 1) * 4096 + i * 64;

  const int srow = l >> 3;
  const int scb = ((l & 7) ^ srow) * 8;
  const int sdst = w * 512;
  const unsigned short* Asrc = A + (long)(m0 + w * 8 + srow) * K + scb;
  const unsigned short* Bsrc = B + (long)(n0 + w * 8 + srow) * K + scb;

  f32x4 acc[8][4];
  #pragma unroll
  for (int a_ = 0; a_ < 8; a_++)
    #pragma unroll
    for (int b_ = 0; b_ < 4; b_++) acc[a_][b_] = (f32x4){0.f, 0.f, 0.f, 0.f};

  bf16x8 a[4][2], b[4][2];

#define BAR __builtin_amdgcn_s_barrier()
#define VM4 asm volatile("s_waitcnt vmcnt(4)" ::: "memory")
#define VM0 asm volatile("s_waitcnt vmcnt(0)" ::: "memory")

#define STG_A(T, h) do { \
    const unsigned short* s_ = Asrc + (long)((h) * 128) * K + (T) * 64; \
    unsigned short* d_ = lds + (((T) & 1) << 15) + ((h) << 13) + sdst; \
    stage16(s_, d_, l); \
    stage16(s_ + (long)64 * K, d_ + 4096, l); \
  } while (0)
#define STG_B(T, h) do { \
    const unsigned short* s_ = Bsrc + (long)((h) * 128) * K + (T) * 64; \
    unsigned short* d_ = lds + (((T) & 1) << 15) + 16384 + ((h) << 13) + sdst; \
    stage16(s_, d_, l); \
    stage16(s_ + (long)64 * K, d_ + 4096, l); \
  } while (0)

#define RD_A(bufo, mh) do { \
    const unsigned short* p_ = lds + (bufo) + aoff + (mh) * 4096; \
    a[0][0] = *(const bf16x8*)(p_ + swz0);        a[0][1] = *(const bf16x8*)(p_ + swz1); \
    a[1][0] = *(const bf16x8*)(p_ + 1024 + swz0); a[1][1] = *(const bf16x8*)(p_ + 1024 + swz1); \
    a[2][0] = *(const bf16x8*)(p_ + 2048 + swz0); a[2][1] = *(const bf16x8*)(p_ + 2048 + swz1); \
    a[3][0] = *(const bf16x8*)(p_ + 3072 + swz0); a[3][1] = *(const bf16x8*)(p_ + 3072 + swz1); \
  } while (0)
#define RD_B(bufo, nf) do { \
    const unsigned short* p_ = lds + (bufo) + boff + (nf) * 1024; \
    b[nf][0] = *(const bf16x8*)(p_ + swz0); \
    b[nf][1] = *(const bf16x8*)(p_ + swz1); \
  } while (0)

#define MMQ(AB, N0, N1) do { \
    __builtin_amdgcn_s_setprio(1); \
    _Pragma("unroll") \
    for (int q_ = 0; q_ < 4; q_++) { \
      acc[(AB) + q_][N0] = __builtin_amdgcn_mfma_f32_16x16x32_bf16(a[q_][0], b[N0][0], acc[(AB) + q_][N0], 0, 0, 0); \
      acc[(AB) + q_][N1] = __builtin_amdgcn_mfma_f32_16x16x32_bf16(a[q_][0], b[N1][0], acc[(AB) + q_][N1], 0, 0, 0); \
    } \
    _Pragma("unroll") \
    for (int q_ = 0; q_ < 4; q_++) { \
      acc[(AB) + q_][N0] = __builtin_amdgcn_mfma_f32_16x16x32_bf16(a[q_][1], b[N0][1], acc[(AB) + q_][N0], 0, 0, 0); \
      acc[(AB) + q_][N1] = __builtin_amdgcn_mfma_f32_16x16x32_bf16(a[q_][1], b[N1][1], acc[(AB) + q_][N1], 0, 0, 0); \
    } \
    __builtin_amdgcn_s_setprio(0); \
  } while (0)

#define GEMM_ITER(T0v, T1v, FULL, GATEP4, GATEP8) do { \
    const int T0_ = (T0v), T1_ = (T1v); \
    /* p1 */ RD_A(0, 0); RD_B(0, 0); RD_B(0, 1); STG_B(T1_, 1); BAR; MMQ(0, 0, 1); BAR; \
    /* p2 */ RD_B(0, 2); RD_B(0, 3); STG_A(T1_, 1); BAR; MMQ(0, 2, 3); BAR; \
    /* p3 */ RD_A(0, 1); if (FULL) { STG_B(T0_ + 2, 0); } BAR; MMQ(4, 2, 3); BAR; \
    /* p4 */ if (FULL) { STG_A(T0_ + 2, 0); } GATEP4; BAR; MMQ(4, 0, 1); BAR; \
    /* p5 */ RD_A(32768, 0); RD_B(32768, 0); RD_B(32768, 1); if (FULL) { STG_B(T0_ + 2, 1); } BAR; MMQ(0, 0, 1); BAR; \
    /* p6 */ RD_B(32768, 2); RD_B(32768, 3); if (FULL) { STG_A(T0_ + 2, 1); } BAR; MMQ(0, 2, 3); BAR; \
    /* p7 */ RD_A(32768, 1); if (FULL) { STG_B(T1_ + 2, 0); } BAR; MMQ(4, 2, 3); BAR; \
    /* p8 */ if (FULL) { STG_A(T1_ + 2, 0); } GATEP8; BAR; MMQ(4, 0, 1); BAR; \
  } while (0)

  STG_B(0, 0); STG_A(0, 0); STG_B(0, 1); STG_A(0, 1);
  STG_B(1, 0); STG_A(1, 0);
  VM4; BAR;

  for (int j = 0; j < NI - 1; ++j) {
    GEMM_ITER(2 * j, 2 * j + 1, 1, VM4, VM4);
  }
  GEMM_ITER(NT - 2, NT - 1, 0, VM0, (void)0);

#undef GEMM_ITER
#undef MMQ
#undef RD_B
#undef RD_A
#undef STG_B
#undef STG_A
#undef VM0
#undef VM4
#undef BAR

  #pragma unroll
  for (int nf = 0; nf < 4; nf++) {
    int col = n0 + wc * 64 + nf * 16 + i;
    float bv = bias[col];
    #pragma unroll
    for (int mf = 0; mf < 8; mf++) {
      int rowb = m0 + wr * 128 + mf * 16 + kq * 4;
      #pragma unroll
      for (int r = 0; r < 4; r++) {
        int row = rowb + r;
        if (row < M_valid) {
          float v = acc[mf][nf][r] + bv;
          if (OUTF) ((float*)C)[(long)row * N + col] = v;
          else      ((unsigned short*)C)[(long)row * N + col] = f2bf(v);
        }
      }
    }
  }
}

// ---------------- RoPE on K (in place, fixed positions 2 / 22) ----------------
__global__ void rope_k_kernel(unsigned short* __restrict__ kv) {
  int r = blockIdx.x;
  int c = threadIdx.x * 8;
  float pos = ((r & 31) < 16) ? 2.0f : 22.0f;
  unsigned short* p = kv + (long)r * 4096 + c;
  bf16x8 v = *(const bf16x8*)p;
  int jb = (c & 63) >> 1;
  bf16x8 o;
  #pragma unroll
  for (int t = 0; t < 4; t++) {
    float invf = __expf(-(float)(jb + t) * LN10000_32);
    float f = pos * invf;
    float s_, c_;
    sincosf(f, &s_, &c_);
    float x1 = bf2f((unsigned short)v[2 * t]);
    float x2 = bf2f((unsigned short)v[2 * t + 1]);
    o[2 * t]     = (short)f2bf(x1 * c_ - x2 * s_);
    o[2 * t + 1] = (short)f2bf(x1 * s_ + x2 * c_);
  }
  *(bf16x8*)p = o;
}

// ---------------- MFMA attention: K pre-roped; RoPE(Q) fused; in place -------
// Grid (13, 672): block = (b,h) x 128 q-rows, 4 waves x 32 rows each.
__global__ __launch_bounds__(256)
void attn_mfma(const unsigned short* __restrict__ kv, unsigned short* __restrict__ q,
               const float2* __restrict__ tab) {
  __shared__ unsigned short Vt[64 * 40];       // V^T [d][a], padded stride 40
  __shared__ unsigned short Pl[4][32 * 40];    // per-wave P [s][a], stride 40
  const int bh = blockIdx.y;
  const int b = bh >> 5, h = bh & 31;
  const int tid = threadIdx.x;
  const int w = tid >> 6, l = tid & 63;
  const int i16 = l & 15, kq = l >> 4;

  // build V^T (V is NOT roped)
  {
    int a = tid & 31, d0 = (tid >> 5) * 8;
    const unsigned short* vp = kv + ((long)(b * 32 + a)) * 4096 + 2048 + h * 64 + d0;
    bf16x8 v = *(const bf16x8*)vp;
    #pragma unroll
    for (int j = 0; j < 8; j++) Vt[(d0 + j) * 40 + a] = (unsigned short)v[j];
  }

  // K fragments (pre-roped in kvbuf): lane holds K[a=nf*16+i16][d=ks*32+kq*8+e]
  bf16x8 bk[2][2];
  #pragma unroll
  for (int nf = 0; nf < 2; nf++) {
    const unsigned short* kp = kv + ((long)(b * 32 + nf * 16 + i16)) * 4096 + h * 64;
    bk[nf][0] = *(const bf16x8*)(kp + kq * 8);
    bk[nf][1] = *(const bf16x8*)(kp + 32 + kq * 8);
  }

  __syncthreads();  // Vt ready for all waves

  // Q fragments with fused RoPE (table)
  const int s0 = blockIdx.x * 128 + w * 32;
  bf16x8 aq[2][2];
  #pragma unroll
  for (int mf = 0; mf < 2; mf++) {
    int srow = s0 + mf * 16 + i16;
    int sc_ = srow < 1560 ? srow : 1559;   // clamp; garbage rows never written
    long row = (long)b * 1560 + sc_;
    const unsigned short* qp = q + row * 2048 + h * 64;
    const float2* trow = tab + row * 32;
    #pragma unroll
    for (int ks = 0; ks < 2; ks++) {
      int d0 = ks * 32 + kq * 8;
      bf16x8 v = *(const bf16x8*)(qp + d0);
      float4 t0 = *(const float4*)&trow[(d0 >> 1)];
      float4 t1 = *(const float4*)&trow[(d0 >> 1) + 2];
      float cs[4] = {t0.x, t0.z, t1.x, t1.z};
      float sn[4] = {t0.y, t0.w, t1.y, t1.w};
      bf16x8 o;
      #pragma unroll
      for (int t = 0; t < 4; t++) {
        float x1 = bf2f((unsigned short)v[2 * t]), x2 = bf2f((unsigned short)v[2 * t + 1]);
        o[2 * t]     = (short)f2bf(x1 * cs[t] - x2 * sn[t]);
        o[2 * t + 1] = (short)f2bf(x1 * sn[t] + x2 * cs[t]);
      }
      aq[mf][ks] = o;
    }
  }

  // QK^T
  f32x4 sfr[2][2];
  #pragma unroll
  for (int mf = 0; mf < 2; mf++)
    #pragma unroll
    for (int nf = 0; nf < 2; nf++) {
      f32x4 c = {0.f, 0.f, 0.f, 0.f};
      c = __builtin_amdgcn_mfma_f32_16x16x32_bf16(aq[mf][0], bk[nf][0], c, 0, 0, 0);
      c = __builtin_amdgcn_mfma_f32_16x16x32_bf16(aq[mf][1], bk[nf][1], c, 0, 0, 0);
      sfr[mf][nf] = c;
    }

  // softmax over keys (across i16 lanes x 2 nf)
  float inv_s[2][4];
  #pragma unroll
  for (int mf = 0; mf < 2; mf++) {
    #pragma unroll
    for (int r = 0; r < 4; r++) {
      float v0 = sfr[mf][0][r] * 0.125f;
      float v1 = sfr[mf][1][r] * 0.125f;
      float mx = fmaxf(v0, v1);
      #pragma unroll
      for (int m_ = 1; m_ < 16; m_ <<= 1) mx = fmaxf(mx, __shfl_xor(mx, m_));
      float e0 = __expf(v0 - mx), e1 = __expf(v1 - mx);
      float sm = e0 + e1;
      #pragma unroll
      for (int m_ = 1; m_ < 16; m_ <<= 1) sm += __shfl_xor(sm, m_);
      inv_s[mf][r] = 1.0f / sm;
      sfr[mf][0][r] = e0; sfr[mf][1][r] = e1;
    }
  }

  // P -> wave-local LDS (wave-exclusive region, no barrier needed)
  unsigned short* pl = &Pl[w][0];
  #pragma unroll
  for (int mf = 0; mf < 2; mf++)
    #pragma unroll
    for (int nf = 0; nf < 2; nf++)
      #pragma unroll
      for (int r = 0; r < 4; r++)
        pl[(mf * 16 + kq * 4 + r) * 40 + nf * 16 + i16] = f2bf(sfr[mf][nf][r]);

  // PV
  bf16x8 pa[2];
  #pragma unroll
  for (int mf = 0; mf < 2; mf++)
    pa[mf] = *(const bf16x8*)&pl[(mf * 16 + i16) * 40 + kq * 8];
  bf16x8 vb[4];
  #pragma unroll
  for (int nf = 0; nf < 4; nf++)
    vb[nf] = *(const bf16x8*)&Vt[(nf * 16 + i16) * 40 + kq * 8];
  f32x4 ofr[2][4];
  #pragma unroll
  for (int mf = 0; mf < 2; mf++)
    #pragma unroll
    for (int nf = 0; nf < 4; nf++) {
      f32x4 c = {0.f, 0.f, 0.f, 0.f};
      ofr[mf][nf] = __builtin_amdgcn_mfma_f32_16x16x32_bf16(pa[mf], vb[nf], c, 0, 0, 0);
    }

  // normalize + guarded write (rows wave-exclusive -> in-place safe)
  #pragma unroll
  for (int mf = 0; mf < 2; mf++) {
    #pragma unroll
    for (int r = 0; r < 4; r++) {
      int srow = s0 + mf * 16 + kq * 4 + r;
      if (srow < 1560) {
        unsigned short* op = q + ((long)b * 1560 + srow) * 2048 + h * 64;
        float inv = inv_s[mf][r];
        #pragma unroll
        for (int nf = 0; nf < 4; nf++)
          op[nf * 16 + i16] = f2bf(ofr[mf][nf][r] * inv);
      }
    }
  }
}

// ---------------- launch ------------------------------------------------------
extern "C" void kernel_launch(void* const* d_in, const int* in_sizes, int n_in,
                              void* d_out, int out_size, void* d_ws, size_t ws_size,
                              hipStream_t stream) {
  const float* x      = (const float*)d_in[0];
  const float* ehs    = (const float*)d_in[1];
  const float* xmap   = (const float*)d_in[2];
  const float* q_w    = (const float*)d_in[3];
  const float* q_b    = (const float*)d_in[4];
  const float* kv_w   = (const float*)d_in[5];
  const float* kv_b   = (const float*)d_in[6];
  const float* proj_w = (const float*)d_in[7];
  const float* proj_b = (const float*)d_in[8];
  float* out = (float*)d_out;

  char* ws = (char*)d_ws;
  float*          mm    = (float*)(ws + 0);
  float2*         tab   = (float2*)(ws + 256);
  unsigned short* qbuf  = (unsigned short*)(ws + 8388864);
  unsigned short* kvbuf = (unsigned short*)(ws + 142606592);
  unsigned short* ehsb  = (unsigned short*)(ws + 148898048);
  unsigned short* qwb   = (unsigned short*)(ws + 150077696);
  unsigned short* kvwb  = (unsigned short*)(ws + 158466304);
  unsigned short* pwb   = (unsigned short*)(ws + 164757760);
  unsigned short* xb    = (unsigned short*)d_out;

  (void)hipFuncSetAttribute((const void*)gemm256<0>, hipFuncAttributeMaxDynamicSharedMemorySize, 131072);
  (void)hipFuncSetAttribute((const void*)gemm256<1>, hipFuncAttributeMaxDynamicSharedMemorySize, 131072);

  minmax_kernel<<<1, 256, 0, stream>>>(xmap, mm);
  pos_table_kernel<<<128, 256, 0, stream>>>(xmap, mm, tab);
  cast_x_kernel<<<2048, 256, 0, stream>>>(x, xb);
  cast_weights_kernel<<<5632, 256, 0, stream>>>(q_w, kv_w, proj_w, qwb, kvwb, pwb);
  cast_ehs_kernel<<<288, 256, 0, stream>>>(ehs, ehsb);

  gemm256<0><<<1024, 512, 131072, stream>>>(xb, qwb, q_b, qbuf, 2048, 2048, 32768);
  gemm_bt<0><<<dim3(6, 32), 256, 0, stream>>>(ehsb, kvwb, kv_b, kvbuf, 768, 4096, 768, 768);

  rope_k_kernel<<<672, 256, 0, stream>>>(kvbuf);

  attn_mfma<<<dim3(13, 672), 256, 0, stream>>>(kvbuf, qbuf, tab);

  gemm256<1><<<1024, 512, 131072, stream>>>(qbuf, pwb, proj_b, out, 2048, 2048, 32760);
}

// Round 12
// 872.349 us; speedup vs baseline: 1.0046x; 1.0046x over previous
//
#include <hip/hip_runtime.h>

typedef short bf16x8 __attribute__((ext_vector_type(8)));
typedef float f32x4 __attribute__((ext_vector_type(4)));

#define LN10000_32 0.2878231406211853f  // ln(10000)/32

__device__ __forceinline__ unsigned short f2bf(float f) {
  union { float f; unsigned int u; } v; v.f = f;
  unsigned int r = v.u + 0x7fffu + ((v.u >> 16) & 1u);
  return (unsigned short)(r >> 16);
}
__device__ __forceinline__ float bf2f(unsigned short h) {
  union { unsigned int u; float f; } v; v.u = ((unsigned int)h) << 16;
  return v.f;
}

__device__ __forceinline__ void stage16(const unsigned short* g, unsigned short* lds_base, int lane) {
#if __has_builtin(__builtin_amdgcn_global_load_lds)
  (void)lane;
  __builtin_amdgcn_global_load_lds((const __attribute__((address_space(1))) void*)g,
                                   (__attribute__((address_space(3))) void*)lds_base,
                                   16, 0, 0);
#else
  *(bf16x8*)((char*)lds_base + lane * 16) = *(const bf16x8*)g;
#endif
}

// ---------------- pos table (minmax fused: every block reduces the map) ------
__global__ void pos_table_kernel(const float* __restrict__ xmap, float2* __restrict__ tab) {
  __shared__ float red[4][256];
  int t = threadIdx.x;
  float mn0 = 3.4e38f, mx0 = -3.4e38f, mn1 = 3.4e38f, mx1 = -3.4e38f;
  for (int i = t; i < 32760; i += 256) {
    float a = xmap[i];          mn0 = fminf(mn0, a); mx0 = fmaxf(mx0, a);
    float b = xmap[32760 + i];  mn1 = fminf(mn1, b); mx1 = fmaxf(mx1, b);
  }
  red[0][t] = mn0; red[1][t] = mx0; red[2][t] = mn1; red[3][t] = mx1;
  __syncthreads();
  for (int s = 128; s > 0; s >>= 1) {
    if (t < s) {
      red[0][t] = fminf(red[0][t], red[0][t + s]);
      red[1][t] = fmaxf(red[1][t], red[1][t + s]);
      red[2][t] = fminf(red[2][t], red[2][t + s]);
      red[3][t] = fmaxf(red[3][t], red[3][t + s]);
    }
    __syncthreads();
  }
  float m0lo = red[0][0], m0hi = red[1][0], m1lo = red[2][0], m1hi = red[3][0];

  int n = blockIdx.x * 256 + t;
  if (n >= 32760) return;
  float a0 = xmap[n], a1 = xmap[32760 + n];
  float pos;
  if (a1 > a0) pos = (a1 - m1lo) / (m1hi - m1lo + 1e-8f) * 4.0f + 20.0f;
  else         pos = (a0 - m0lo) / (m0hi - m0lo + 1e-8f) * 4.0f;
  #pragma unroll
  for (int j = 0; j < 32; j++) {
    float invf = __expf(-(float)j * LN10000_32);
    float f = pos * invf;
    float s, c;
    sincosf(f, &s, &c);
    tab[(long)n * 32 + j] = make_float2(c, s);
  }
}

// ---------------- all input casts in one grid-stride launch -------------------
// ranges (in groups of 8 elems): x [0, 8388608) as 32768x256 (rows>=32760 zero)
// weights [8388608, +1441792): q_w 524288 | kv_w 393216 | proj_w 524288
// ehs [.., +73728): 768 rows x 96 groups (rows>=672 zero)
__global__ void cast_all_kernel(const float* __restrict__ x, const float* __restrict__ qw,
                                const float* __restrict__ kvw, const float* __restrict__ pw,
                                const float* __restrict__ ehs,
                                unsigned short* __restrict__ xb, unsigned short* __restrict__ qwb,
                                unsigned short* __restrict__ kvwb, unsigned short* __restrict__ pwb,
                                unsigned short* __restrict__ ehsb) {
  const long NX = 8388608, NW = 1441792, NE = 73728;
  const long total = NX + NW + NE;
  for (long g = (long)blockIdx.x * 256 + threadIdx.x; g < total; g += (long)gridDim.x * 256) {
    const float* src = nullptr;
    unsigned short* dst;
    long j;
    bool zero = false;
    if (g < NX) {
      long r = g >> 8;
      zero = (r >= 32760);
      src = x; dst = xb; j = g;
    } else if (g < NX + NW) {
      long i = g - NX;
      if (i < 524288)      { src = qw;  dst = qwb;  j = i; }
      else if (i < 917504) { src = kvw; dst = kvwb; j = i - 524288; }
      else                 { src = pw;  dst = pwb;  j = i - 917504; }
    } else {
      long i = g - NX - NW;
      long r = i / 96;
      zero = (r >= 672);
      src = ehs; dst = ehsb; j = i;
    }
    bf16x8 o;
    if (!zero) {
      const float4* s = (const float4*)(src + j * 8);
      float4 a = s[0], b = s[1];
      o[0] = (short)f2bf(a.x); o[1] = (short)f2bf(a.y); o[2] = (short)f2bf(a.z); o[3] = (short)f2bf(a.w);
      o[4] = (short)f2bf(b.x); o[5] = (short)f2bf(b.y); o[6] = (short)f2bf(b.z); o[7] = (short)f2bf(b.w);
    } else {
      #pragma unroll
      for (int t = 0; t < 8; t++) o[t] = 0;
    }
    *(bf16x8*)(dst + j * 8) = o;
  }
}

// ---------------- small GEMM (128x128 m97-style) for KV projection -----------
template <int OUTF>
__global__ __launch_bounds__(256, 2)
void gemm_bt(const unsigned short* __restrict__ A, const unsigned short* __restrict__ B,
             const float* __restrict__ bias, void* __restrict__ C,
             int M, int N, int K, int M_valid) {
  __shared__ unsigned short As[128 * 32];
  __shared__ unsigned short Bs[128 * 32];
  int mt = blockIdx.x, nt = blockIdx.y;
  const int m0 = mt * 128;
  const int n0 = nt * 128;
  const int tid = threadIdx.x;
  const int wave = tid >> 6;
  const int lane = tid & 63;
  const int wr = wave >> 1, wc = wave & 1;
  const int lrow = lane >> 2, lcol = lane & 3;

  f32x4 acc[4][4];
  #pragma unroll
  for (int i = 0; i < 4; i++)
    #pragma unroll
    for (int j = 0; j < 4; j++) acc[i][j] = (f32x4){0.f, 0.f, 0.f, 0.f};

  const unsigned short* gA = A + (long)(m0 + wave * 32 + lrow) * K + lcol * 8;
  const unsigned short* gB = B + (long)(n0 + wave * 32 + lrow) * K + lcol * 8;
  unsigned short* lA0 = &As[wave * 1024];
  unsigned short* lA1 = &As[wave * 1024 + 512];
  unsigned short* lB0 = &Bs[wave * 1024];
  unsigned short* lB1 = &Bs[wave * 1024 + 512];

  for (int k0 = 0; k0 < K; k0 += 32) {
    stage16(gA + k0, lA0, lane);
    stage16(gA + k0 + 16 * K, lA1, lane);
    stage16(gB + k0, lB0, lane);
    stage16(gB + k0 + 16 * K, lB1, lane);
    __syncthreads();
    bf16x8 af[4], bfr[4];
    const int kq = (lane >> 4) * 8;
    const int rr = lane & 15;
    #pragma unroll
    for (int mi = 0; mi < 4; mi++) af[mi] = *(const bf16x8*)&As[(wr * 64 + mi * 16 + rr) * 32 + kq];
    #pragma unroll
    for (int ni = 0; ni < 4; ni++) bfr[ni] = *(const bf16x8*)&Bs[(wc * 64 + ni * 16 + rr) * 32 + kq];
    #pragma unroll
    for (int mi = 0; mi < 4; mi++)
      #pragma unroll
      for (int ni = 0; ni < 4; ni++)
        acc[mi][ni] = __builtin_amdgcn_mfma_f32_16x16x32_bf16(af[mi], bfr[ni], acc[mi][ni], 0, 0, 0);
    __syncthreads();
  }

  const int colL = lane & 15, rq = (lane >> 4) * 4;
  #pragma unroll
  for (int mi = 0; mi < 4; mi++) {
    #pragma unroll
    for (int ni = 0; ni < 4; ni++) {
      int col = n0 + wc * 64 + ni * 16 + colL;
      float bv = bias[col];
      #pragma unroll
      for (int r = 0; r < 4; r++) {
        int row = m0 + wr * 64 + mi * 16 + rq + r;
        if (row < M_valid) {
          float v = acc[mi][ni][r] + bv;
          if (OUTF) ((float*)C)[(long)row * N + col] = v;
          else      ((unsigned short*)C)[(long)row * N + col] = f2bf(v);
        }
      }
    }
  }
}

// ---------------- big GEMM: 256x256, BK=64, dbuf, 8-phase counted-vmcnt ------
// Frozen (r3 version): ~330 us, 36% MfmaUtil. Analysis: per-tile staging needs
// ~248 GB/s/CU from L2 vs ~134 available -> L2-BW-limited; schedule variants
// (r4/r5/r8) all land 833-848 TF. Do not touch.
template <int OUTF>
__global__ __launch_bounds__(512, 2)
void gemm256(const unsigned short* __restrict__ A, const unsigned short* __restrict__ B,
             const float* __restrict__ bias, void* __restrict__ C,
             int K, int N, int M_valid) {
  extern __shared__ __align__(16) unsigned short lds[];  // 65536 ushorts
  const int NT = K >> 6;
  const int NI = NT >> 1;
  const int orig = blockIdx.x;
  const int cpx = (int)gridDim.x >> 3;
  const int wgid = (orig & 7) * cpx + (orig >> 3);
  const int nt = wgid & 7;
  const int mt = wgid >> 3;
  const int m0 = mt << 8, n0 = nt << 8;
  const int tid = threadIdx.x;
  const int w = tid >> 6, l = tid & 63;
  const int wr = w >> 2, wc = w & 3;
  const int i = l & 15, kq = l >> 4;

  const int swz0 = ((kq) ^ (i & 7)) * 8;
  const int swz1 = ((4 + kq) ^ (i & 7)) * 8;
  const int aoff = wr * 8192 + i * 64;
  const int boff = 16384 + (wc >> 1) * 8192 + (wc & 1) * 4096 + i * 64;

  const int srow = l >> 3;
  const int scb = ((l & 7) ^ srow) * 8;
  const int sdst = w * 512;
  const unsigned short* Asrc = A + (long)(m0 + w * 8 + srow) * K + scb;
  const unsigned short* Bsrc = B + (long)(n0 + w * 8 + srow) * K + scb;

  f32x4 acc[8][4];
  #pragma unroll
  for (int a_ = 0; a_ < 8; a_++)
    #pragma unroll
    for (int b_ = 0; b_ < 4; b_++) acc[a_][b_] = (f32x4){0.f, 0.f, 0.f, 0.f};

  bf16x8 a[4][2], b[4][2];

#define BAR __builtin_amdgcn_s_barrier()
#define VM4 asm volatile("s_waitcnt vmcnt(4)" ::: "memory")
#define VM0 asm volatile("s_waitcnt vmcnt(0)" ::: "memory")

#define STG_A(T, h) do { \
    const unsigned short* s_ = Asrc + (long)((h) * 128) * K + (T) * 64; \
    unsigned short* d_ = lds + (((T) & 1) << 15) + ((h) << 13) + sdst; \
    stage16(s_, d_, l); \
    stage16(s_ + (long)64 * K, d_ + 4096, l); \
  } while (0)
#define STG_B(T, h) do { \
    const unsigned short* s_ = Bsrc + (long)((h) * 128) * K + (T) * 64; \
    unsigned short* d_ = lds + (((T) & 1) << 15) + 16384 + ((h) << 13) + sdst; \
    stage16(s_, d_, l); \
    stage16(s_ + (long)64 * K, d_ + 4096, l); \
  } while (0)

#define RD_A(bufo, mh) do { \
    const unsigned short* p_ = lds + (bufo) + aoff + (mh) * 4096; \
    a[0][0] = *(const bf16x8*)(p_ + swz0);        a[0][1] = *(const bf16x8*)(p_ + swz1); \
    a[1][0] = *(const bf16x8*)(p_ + 1024 + swz0); a[1][1] = *(const bf16x8*)(p_ + 1024 + swz1); \
    a[2][0] = *(const bf16x8*)(p_ + 2048 + swz0); a[2][1] = *(const bf16x8*)(p_ + 2048 + swz1); \
    a[3][0] = *(const bf16x8*)(p_ + 3072 + swz0); a[3][1] = *(const bf16x8*)(p_ + 3072 + swz1); \
  } while (0)
#define RD_B(bufo, nf) do { \
    const unsigned short* p_ = lds + (bufo) + boff + (nf) * 1024; \
    b[nf][0] = *(const bf16x8*)(p_ + swz0); \
    b[nf][1] = *(const bf16x8*)(p_ + swz1); \
  } while (0)

#define MMQ(AB, N0, N1) do { \
    __builtin_amdgcn_s_setprio(1); \
    _Pragma("unroll") \
    for (int q_ = 0; q_ < 4; q_++) { \
      acc[(AB) + q_][N0] = __builtin_amdgcn_mfma_f32_16x16x32_bf16(a[q_][0], b[N0][0], acc[(AB) + q_][N0], 0, 0, 0); \
      acc[(AB) + q_][N1] = __builtin_amdgcn_mfma_f32_16x16x32_bf16(a[q_][0], b[N1][0], acc[(AB) + q_][N1], 0, 0, 0); \
    } \
    _Pragma("unroll") \
    for (int q_ = 0; q_ < 4; q_++) { \
      acc[(AB) + q_][N0] = __builtin_amdgcn_mfma_f32_16x16x32_bf16(a[q_][1], b[N0][1], acc[(AB) + q_][N0], 0, 0, 0); \
      acc[(AB) + q_][N1] = __builtin_amdgcn_mfma_f32_16x16x32_bf16(a[q_][1], b[N1][1], acc[(AB) + q_][N1], 0, 0, 0); \
    } \
    __builtin_amdgcn_s_setprio(0); \
  } while (0)

#define GEMM_ITER(T0v, T1v, FULL, GATEP4, GATEP8) do { \
    const int T0_ = (T0v), T1_ = (T1v); \
    /* p1 */ RD_A(0, 0); RD_B(0, 0); RD_B(0, 1); STG_B(T1_, 1); BAR; MMQ(0, 0, 1); BAR; \
    /* p2 */ RD_B(0, 2); RD_B(0, 3); STG_A(T1_, 1); BAR; MMQ(0, 2, 3); BAR; \
    /* p3 */ RD_A(0, 1); if (FULL) { STG_B(T0_ + 2, 0); } BAR; MMQ(4, 2, 3); BAR; \
    /* p4 */ if (FULL) { STG_A(T0_ + 2, 0); } GATEP4; BAR; MMQ(4, 0, 1); BAR; \
    /* p5 */ RD_A(32768, 0); RD_B(32768, 0); RD_B(32768, 1); if (FULL) { STG_B(T0_ + 2, 1); } BAR; MMQ(0, 0, 1); BAR; \
    /* p6 */ RD_B(32768, 2); RD_B(32768, 3); if (FULL) { STG_A(T0_ + 2, 1); } BAR; MMQ(0, 2, 3); BAR; \
    /* p7 */ RD_A(32768, 1); if (FULL) { STG_B(T1_ + 2, 0); } BAR; MMQ(4, 2, 3); BAR; \
    /* p8 */ if (FULL) { STG_A(T1_ + 2, 0); } GATEP8; BAR; MMQ(4, 0, 1); BAR; \
  } while (0)

  STG_B(0, 0); STG_A(0, 0); STG_B(0, 1); STG_A(0, 1);
  STG_B(1, 0); STG_A(1, 0);
  VM4; BAR;

  for (int j = 0; j < NI - 1; ++j) {
    GEMM_ITER(2 * j, 2 * j + 1, 1, VM4, VM4);
  }
  GEMM_ITER(NT - 2, NT - 1, 0, VM0, (void)0);

#undef GEMM_ITER
#undef MMQ
#undef RD_B
#undef RD_A
#undef STG_B
#undef STG_A
#undef VM0
#undef VM4
#undef BAR

  #pragma unroll
  for (int nf = 0; nf < 4; nf++) {
    int col = n0 + wc * 64 + nf * 16 + i;
    float bv = bias[col];
    #pragma unroll
    for (int mf = 0; mf < 8; mf++) {
      int rowb = m0 + wr * 128 + mf * 16 + kq * 4;
      #pragma unroll
      for (int r = 0; r < 4; r++) {
        int row = rowb + r;
        if (row < M_valid) {
          float v = acc[mf][nf][r] + bv;
          if (OUTF) ((float*)C)[(long)row * N + col] = v;
          else      ((unsigned short*)C)[(long)row * N + col] = f2bf(v);
        }
      }
    }
  }
}

// ---------------- RoPE on K (in place, fixed positions 2 / 22) ----------------
__global__ void rope_k_kernel(unsigned short* __restrict__ kv) {
  int r = blockIdx.x;
  int c = threadIdx.x * 8;
  float pos = ((r & 31) < 16) ? 2.0f : 22.0f;
  unsigned short* p = kv + (long)r * 4096 + c;
  bf16x8 v = *(const bf16x8*)p;
  int jb = (c & 63) >> 1;
  bf16x8 o;
  #pragma unroll
  for (int t = 0; t < 4; t++) {
    float invf = __expf(-(float)(jb + t) * LN10000_32);
    float f = pos * invf;
    float s_, c_;
    sincosf(f, &s_, &c_);
    float x1 = bf2f((unsigned short)v[2 * t]);
    float x2 = bf2f((unsigned short)v[2 * t + 1]);
    o[2 * t]     = (short)f2bf(x1 * c_ - x2 * s_);
    o[2 * t + 1] = (short)f2bf(x1 * s_ + x2 * c_);
  }
  *(bf16x8*)p = o;
}

// ---------------- MFMA attention: K pre-roped; RoPE(Q) fused; in place -------
__global__ __launch_bounds__(256)
void attn_mfma(const unsigned short* __restrict__ kv, unsigned short* __restrict__ q,
               const float2* __restrict__ tab) {
  __shared__ unsigned short Vt[64 * 40];       // V^T [d][a], padded stride 40
  __shared__ unsigned short Pl[4][32 * 40];    // per-wave P [s][a], stride 40
  const int bh = blockIdx.y;
  const int b = bh >> 5, h = bh & 31;
  const int tid = threadIdx.x;
  const int w = tid >> 6, l = tid & 63;
  const int i16 = l & 15, kq = l >> 4;

  // build V^T (V is NOT roped)
  {
    int a = tid & 31, d0 = (tid >> 5) * 8;
    const unsigned short* vp = kv + ((long)(b * 32 + a)) * 4096 + 2048 + h * 64 + d0;
    bf16x8 v = *(const bf16x8*)vp;
    #pragma unroll
    for (int j = 0; j < 8; j++) Vt[(d0 + j) * 40 + a] = (unsigned short)v[j];
  }

  // K fragments (pre-roped in kvbuf)
  bf16x8 bk[2][2];
  #pragma unroll
  for (int nf = 0; nf < 2; nf++) {
    const unsigned short* kp = kv + ((long)(b * 32 + nf * 16 + i16)) * 4096 + h * 64;
    bk[nf][0] = *(const bf16x8*)(kp + kq * 8);
    bk[nf][1] = *(const bf16x8*)(kp + 32 + kq * 8);
  }

  __syncthreads();  // Vt ready for all waves

  // Q fragments with fused RoPE (table)
  const int s0 = blockIdx.x * 128 + w * 32;
  bf16x8 aq[2][2];
  #pragma unroll
  for (int mf = 0; mf < 2; mf++) {
    int srow = s0 + mf * 16 + i16;
    int sc_ = srow < 1560 ? srow : 1559;   // clamp; garbage rows never written
    long row = (long)b * 1560 + sc_;
    const unsigned short* qp = q + row * 2048 + h * 64;
    const float2* trow = tab + row * 32;
    #pragma unroll
    for (int ks = 0; ks < 2; ks++) {
      int d0 = ks * 32 + kq * 8;
      bf16x8 v = *(const bf16x8*)(qp + d0);
      float4 t0 = *(const float4*)&trow[(d0 >> 1)];
      float4 t1 = *(const float4*)&trow[(d0 >> 1) + 2];
      float cs[4] = {t0.x, t0.z, t1.x, t1.z};
      float sn[4] = {t0.y, t0.w, t1.y, t1.w};
      bf16x8 o;
      #pragma unroll
      for (int t = 0; t < 4; t++) {
        float x1 = bf2f((unsigned short)v[2 * t]), x2 = bf2f((unsigned short)v[2 * t + 1]);
        o[2 * t]     = (short)f2bf(x1 * cs[t] - x2 * sn[t]);
        o[2 * t + 1] = (short)f2bf(x1 * sn[t] + x2 * cs[t]);
      }
      aq[mf][ks] = o;
    }
  }

  // QK^T
  f32x4 sfr[2][2];
  #pragma unroll
  for (int mf = 0; mf < 2; mf++)
    #pragma unroll
    for (int nf = 0; nf < 2; nf++) {
      f32x4 c = {0.f, 0.f, 0.f, 0.f};
      c = __builtin_amdgcn_mfma_f32_16x16x32_bf16(aq[mf][0], bk[nf][0], c, 0, 0, 0);
      c = __builtin_amdgcn_mfma_f32_16x16x32_bf16(aq[mf][1], bk[nf][1], c, 0, 0, 0);
      sfr[mf][nf] = c;
    }

  // softmax over keys (across i16 lanes x 2 nf)
  float inv_s[2][4];
  #pragma unroll
  for (int mf = 0; mf < 2; mf++) {
    #pragma unroll
    for (int r = 0; r < 4; r++) {
      float v0 = sfr[mf][0][r] * 0.125f;
      float v1 = sfr[mf][1][r] * 0.125f;
      float mx = fmaxf(v0, v1);
      #pragma unroll
      for (int m_ = 1; m_ < 16; m_ <<= 1) mx = fmaxf(mx, __shfl_xor(mx, m_));
      float e0 = __expf(v0 - mx), e1 = __expf(v1 - mx);
      float sm = e0 + e1;
      #pragma unroll
      for (int m_ = 1; m_ < 16; m_ <<= 1) sm += __shfl_xor(sm, m_);
      inv_s[mf][r] = 1.0f / sm;
      sfr[mf][0][r] = e0; sfr[mf][1][r] = e1;
    }
  }

  // P -> wave-local LDS (wave-exclusive region, no barrier needed)
  unsigned short* pl = &Pl[w][0];
  #pragma unroll
  for (int mf = 0; mf < 2; mf++)
    #pragma unroll
    for (int nf = 0; nf < 2; nf++)
      #pragma unroll
      for (int r = 0; r < 4; r++)
        pl[(mf * 16 + kq * 4 + r) * 40 + nf * 16 + i16] = f2bf(sfr[mf][nf][r]);

  // PV
  bf16x8 pa[2];
  #pragma unroll
  for (int mf = 0; mf < 2; mf++)
    pa[mf] = *(const bf16x8*)&pl[(mf * 16 + i16) * 40 + kq * 8];
  bf16x8 vb[4];
  #pragma unroll
  for (int nf = 0; nf < 4; nf++)
    vb[nf] = *(const bf16x8*)&Vt[(nf * 16 + i16) * 40 + kq * 8];
  f32x4 ofr[2][4];
  #pragma unroll
  for (int mf = 0; mf < 2; mf++)
    #pragma unroll
    for (int nf = 0; nf < 4; nf++) {
      f32x4 c = {0.f, 0.f, 0.f, 0.f};
      ofr[mf][nf] = __builtin_amdgcn_mfma_f32_16x16x32_bf16(pa[mf], vb[nf], c, 0, 0, 0);
    }

  // normalize + guarded write (rows wave-exclusive -> in-place safe)
  #pragma unroll
  for (int mf = 0; mf < 2; mf++) {
    #pragma unroll
    for (int r = 0; r < 4; r++) {
      int srow = s0 + mf * 16 + kq * 4 + r;
      if (srow < 1560) {
        unsigned short* op = q + ((long)b * 1560 + srow) * 2048 + h * 64;
        float inv = inv_s[mf][r];
        #pragma unroll
        for (int nf = 0; nf < 4; nf++)
          op[nf * 16 + i16] = f2bf(ofr[mf][nf][r] * inv);
      }
    }
  }
}

// ---------------- launch ------------------------------------------------------
extern "C" void kernel_launch(void* const* d_in, const int* in_sizes, int n_in,
                              void* d_out, int out_size, void* d_ws, size_t ws_size,
                              hipStream_t stream) {
  const float* x      = (const float*)d_in[0];
  const float* ehs    = (const float*)d_in[1];
  const float* xmap   = (const float*)d_in[2];
  const float* q_w    = (const float*)d_in[3];
  const float* q_b    = (const float*)d_in[4];
  const float* kv_w   = (const float*)d_in[5];
  const float* kv_b   = (const float*)d_in[6];
  const float* proj_w = (const float*)d_in[7];
  const float* proj_b = (const float*)d_in[8];
  float* out = (float*)d_out;

  char* ws = (char*)d_ws;
  float2*         tab   = (float2*)(ws + 256);
  unsigned short* qbuf  = (unsigned short*)(ws + 8388864);
  unsigned short* kvbuf = (unsigned short*)(ws + 142606592);
  unsigned short* ehsb  = (unsigned short*)(ws + 148898048);
  unsigned short* qwb   = (unsigned short*)(ws + 150077696);
  unsigned short* kvwb  = (unsigned short*)(ws + 158466304);
  unsigned short* pwb   = (unsigned short*)(ws + 164757760);
  unsigned short* xb    = (unsigned short*)d_out;

  (void)hipFuncSetAttribute((const void*)gemm256<0>, hipFuncAttributeMaxDynamicSharedMemorySize, 131072);
  (void)hipFuncSetAttribute((const void*)gemm256<1>, hipFuncAttributeMaxDynamicSharedMemorySize, 131072);

  pos_table_kernel<<<128, 256, 0, stream>>>(xmap, tab);
  cast_all_kernel<<<4096, 256, 0, stream>>>(x, q_w, kv_w, proj_w, ehs,
                                            xb, qwb, kvwb, pwb, ehsb);

  gemm256<0><<<1024, 512, 131072, stream>>>(xb, qwb, q_b, qbuf, 2048, 2048, 32768);
  gemm_bt<0><<<dim3(6, 32), 256, 0, stream>>>(ehsb, kvwb, kv_b, kvbuf, 768, 4096, 768, 768);

  rope_k_kernel<<<672, 256, 0, stream>>>(kvbuf);

  attn_mfma<<<dim3(13, 672), 256, 0, stream>>>(kvbuf, qbuf, tab);

  gemm256<1><<<1024, 512, 131072, stream>>>(qbuf, pwb, proj_b, out, 2048, 2048, 32760);
}